// Round 7
// baseline (163.399 us; speedup 1.0000x reference)
//
#include <hip/hip_runtime.h>

#define BATCH 16
#define HH 512
#define WW 512
#define NPIX (BATCH * HH * WW)

#define OT 32               // 32x32 output tile
#define RAD 4
#define LT (OT + 2 * RAD)   // 40x40 staged tile, stride 40 floats (160B, 16B-aligned rows)

// ---------------------------------------------------------------------------
// Kernel 0: normalize the 9x9 filter: f = (filt + 10) / sum(filt + 10)
// ---------------------------------------------------------------------------
__global__ void norm_filter_kernel(const float* __restrict__ filt,
                                   float* __restrict__ f) {
    __shared__ float sh[128];
    int tid = threadIdx.x;
    float v = (tid < 81) ? (filt[tid] + 10.0f) : 0.0f;
    sh[tid] = v;
    __syncthreads();
    for (int o = 64; o > 0; o >>= 1) {
        if (tid < o) sh[tid] += sh[tid + o];
        __syncthreads();
    }
    float sum = sh[0];
    if (tid < 81) f[tid] = v / sum;
}

// ---------------------------------------------------------------------------
// Conv core mapping: 256 threads = 8 col-groups x 32 rows.
// Thread (row, cg) computes output row `row`, cols 4*cg..4*cg+3 via three
// ds_read_b128 per tap-row (verified: each 16-lane phase touches every bank
// exactly 2x => conflict-free per m136). Taps f[const] -> SGPR.
// ---------------------------------------------------------------------------

// Kernel 1: channel-sum staging + conv -> m; t = sum_c (x_c - m)^2 from
// re-read x centers (48B-aligned float4, L1/L2-hot from staging).
__global__ __launch_bounds__(256) void conv_mean_kernel(
        const float* __restrict__ x, const float* __restrict__ f,
        float* __restrict__ m, float* __restrict__ t) {
    __shared__ float tile[LT][LT];

    const int tid = threadIdx.x;
    const int b = blockIdx.z;
    const int h0 = blockIdx.y * OT;
    const int w0 = blockIdx.x * OT;
    const float* xb = x + (size_t)b * HH * WW * 3;

    // stage 40x40 channel-sum, zero outside image (SAME padding)
    for (int i = tid; i < LT * LT; i += 256) {
        const int r = i / LT, c = i - r * LT;
        const int gh = h0 - RAD + r, gw = w0 - RAD + c;
        float v = 0.0f;
        if (gh >= 0 && gh < HH && gw >= 0 && gw < WW) {
            const float* xp = xb + ((size_t)gh * WW + gw) * 3;
            v = xp[0] + xp[1] + xp[2];
        }
        tile[r][c] = v;
    }
    __syncthreads();

    const int cg = tid & 7;          // 0..7
    const int row = tid >> 3;        // 0..31
    const int c0 = 4 * cg;

    float2 a01 = {0.f, 0.f}, a23 = {0.f, 0.f};
#pragma unroll
    for (int dh = 0; dh < 9; dh++) {
        const float4 va = *(const float4*)&tile[row + dh][c0];
        const float4 vb = *(const float4*)&tile[row + dh][c0 + 4];
        const float4 vc = *(const float4*)&tile[row + dh][c0 + 8];
        const float v[12] = {va.x, va.y, va.z, va.w,
                             vb.x, vb.y, vb.z, vb.w,
                             vc.x, vc.y, vc.z, vc.w};
#pragma unroll
        for (int j = 0; j < 9; j++) {
            const float fv = f[dh * 9 + j];   // uniform const index -> s_load
            a01.x += v[j] * fv;
            a01.y += v[j + 1] * fv;
            a23.x += v[j + 2] * fv;
            a23.y += v[j + 3] * fv;
        }
    }

    const int gh = h0 + row;
    const int gw0 = w0 + c0;
    const size_t cbase = ((size_t)gh * WW + gw0) * 3;   // *4B: 48B-aligned
    const float4 xa = *(const float4*)&xb[cbase];
    const float4 xc = *(const float4*)&xb[cbase + 4];
    const float4 xe = *(const float4*)&xb[cbase + 8];

    float4 tv;
    {
        float d0 = xa.x - a01.x, d1 = xa.y - a01.x, d2 = xa.z - a01.x;
        tv.x = d0 * d0 + d1 * d1 + d2 * d2;
        d0 = xa.w - a01.y; d1 = xc.x - a01.y; d2 = xc.y - a01.y;
        tv.y = d0 * d0 + d1 * d1 + d2 * d2;
        d0 = xc.z - a23.x; d1 = xc.w - a23.x; d2 = xe.x - a23.x;
        tv.z = d0 * d0 + d1 * d1 + d2 * d2;
        d0 = xe.y - a23.y; d1 = xe.z - a23.y; d2 = xe.w - a23.y;
        tv.w = d0 * d0 + d1 * d1 + d2 * d2;
    }

    const size_t idx = ((size_t)b * HH + gh) * WW + gw0;
    float4 mv = {a01.x, a01.y, a23.x, a23.y};
    *(float4*)&m[idx] = mv;
    *(float4*)&t[idx] = tv;
}

// ---------------------------------------------------------------------------
// Kernel 2: conv(t) -> sigma = sqrt(.), per-block partial sums (no atomics)
// ---------------------------------------------------------------------------
__global__ __launch_bounds__(256) void conv_sigma_kernel(
        const float* __restrict__ t, const float* __restrict__ f,
        float* __restrict__ sig, float* __restrict__ partial) {
    __shared__ float tile[LT][LT];
    __shared__ float wsum[4];

    const int tid = threadIdx.x;
    const int b = blockIdx.z;
    const int h0 = blockIdx.y * OT;
    const int w0 = blockIdx.x * OT;
    const float* tb = t + (size_t)b * HH * WW;

    for (int i = tid; i < LT * LT; i += 256) {
        const int r = i / LT, c = i - r * LT;
        const int gh = h0 - RAD + r, gw = w0 - RAD + c;
        float v = 0.0f;
        if (gh >= 0 && gh < HH && gw >= 0 && gw < WW)
            v = tb[(size_t)gh * WW + gw];
        tile[r][c] = v;
    }
    __syncthreads();

    const int cg = tid & 7;
    const int row = tid >> 3;
    const int c0 = 4 * cg;

    float2 a01 = {0.f, 0.f}, a23 = {0.f, 0.f};
#pragma unroll
    for (int dh = 0; dh < 9; dh++) {
        const float4 va = *(const float4*)&tile[row + dh][c0];
        const float4 vb = *(const float4*)&tile[row + dh][c0 + 4];
        const float4 vc = *(const float4*)&tile[row + dh][c0 + 8];
        const float v[12] = {va.x, va.y, va.z, va.w,
                             vb.x, vb.y, vb.z, vb.w,
                             vc.x, vc.y, vc.z, vc.w};
#pragma unroll
        for (int j = 0; j < 9; j++) {
            const float fv = f[dh * 9 + j];
            a01.x += v[j] * fv;
            a01.y += v[j + 1] * fv;
            a23.x += v[j + 2] * fv;
            a23.y += v[j + 3] * fv;
        }
    }

    float4 sg;
    sg.x = sqrtf(fmaxf(a01.x, 0.0f));
    sg.y = sqrtf(fmaxf(a01.y, 0.0f));
    sg.z = sqrtf(fmaxf(a23.x, 0.0f));
    sg.w = sqrtf(fmaxf(a23.y, 0.0f));

    const int gh = h0 + row;
    *(float4*)&sig[((size_t)b * HH + gh) * WW + (w0 + c0)] = sg;

    float psum = sg.x + sg.y + sg.z + sg.w;
#pragma unroll
    for (int o = 32; o > 0; o >>= 1) psum += __shfl_down(psum, o);
    if ((tid & 63) == 0) wsum[tid >> 6] = psum;
    __syncthreads();
    if (tid == 0)
        partial[b * 256 + blockIdx.y * 16 + blockIdx.x] =
            wsum[0] + wsum[1] + wsum[2] + wsum[3];
}

// ---------------------------------------------------------------------------
// Kernel 2.5: reduce 256 partials per batch -> bsum[b]
// ---------------------------------------------------------------------------
__global__ __launch_bounds__(256) void reduce_bsum_kernel(
        const float* __restrict__ partial, float* __restrict__ bsum) {
    __shared__ float wsum[4];
    const int b = blockIdx.x, tid = threadIdx.x;
    float v = partial[b * 256 + tid];
#pragma unroll
    for (int o = 32; o > 0; o >>= 1) v += __shfl_down(v, o);
    if ((tid & 63) == 0) wsum[tid >> 6] = v;
    __syncthreads();
    if (tid == 0) bsum[b] = wsum[0] + wsum[1] + wsum[2] + wsum[3];
}

// ---------------------------------------------------------------------------
// Kernel 3: out = (x - m) * rcp(max(mean_b, sigma)); 4 pixels / thread
// ---------------------------------------------------------------------------
__global__ __launch_bounds__(256) void final_kernel(
        const float* __restrict__ x, const float* __restrict__ m,
        const float* __restrict__ sig, const float* __restrict__ bsum,
        float* __restrict__ out) {
    const int i = blockIdx.x * 256 + threadIdx.x;   // group of 4 pixels
    const int b = i >> 16;                          // (i*4) / (512*512)
    const float mean = bsum[b] * (1.0f / (HH * WW));

    float4 mv = ((const float4*)m)[i];
    float4 sv = ((const float4*)sig)[i];
    const float4* xp = (const float4*)x + (size_t)i * 3;
    float4 a = xp[0], bb = xp[1], cc = xp[2];

    float r0 = __builtin_amdgcn_rcpf(fmaxf(mean, sv.x));
    float r1 = __builtin_amdgcn_rcpf(fmaxf(mean, sv.y));
    float r2 = __builtin_amdgcn_rcpf(fmaxf(mean, sv.z));
    float r3 = __builtin_amdgcn_rcpf(fmaxf(mean, sv.w));

    float4 o0, o1, o2;
    o0.x = (a.x - mv.x) * r0;
    o0.y = (a.y - mv.x) * r0;
    o0.z = (a.z - mv.x) * r0;
    o0.w = (a.w - mv.y) * r1;
    o1.x = (bb.x - mv.y) * r1;
    o1.y = (bb.y - mv.y) * r1;
    o1.z = (bb.z - mv.z) * r2;
    o1.w = (bb.w - mv.z) * r2;
    o2.x = (cc.x - mv.z) * r2;
    o2.y = (cc.y - mv.w) * r3;
    o2.z = (cc.z - mv.w) * r3;
    o2.w = (cc.w - mv.w) * r3;

    float4* op = (float4*)out + (size_t)i * 3;
    op[0] = o0;
    op[1] = o1;
    op[2] = o2;
}

// ---------------------------------------------------------------------------
extern "C" void kernel_launch(void* const* d_in, const int* in_sizes, int n_in,
                              void* d_out, int out_size, void* d_ws, size_t ws_size,
                              hipStream_t stream) {
    const float* x = (const float*)d_in[0];
    const float* filt = (const float*)d_in[1];
    float* out = (float*)d_out;

    char* ws = (char*)d_ws;
    float* f = (float*)ws;                          // 81 floats
    float* bsum = (float*)(ws + 512);               // 16 floats
    float* partial = (float*)(ws + 1024);           // 4096 floats
    float* m = (float*)(ws + 32768);                // NPIX floats (16.8 MB)
    float* t = m + NPIX;                            // NPIX floats
    float* sig = t + NPIX;                          // NPIX floats

    norm_filter_kernel<<<1, 128, 0, stream>>>(filt, f);

    dim3 cgrid(WW / OT, HH / OT, BATCH);            // (16, 16, 16)
    conv_mean_kernel<<<cgrid, 256, 0, stream>>>(x, f, m, t);
    conv_sigma_kernel<<<cgrid, 256, 0, stream>>>(t, f, sig, partial);
    reduce_bsum_kernel<<<BATCH, 256, 0, stream>>>(partial, bsum);

    final_kernel<<<NPIX / 4 / 256, 256, 0, stream>>>(x, m, sig, bsum, out);
}